// Round 1
// 723.730 us; speedup vs baseline: 1.0105x; 1.0105x over previous
//
#include <hip/hip_runtime.h>
#include <math.h>

#define NTHR 256

typedef __bf16 bf16x8 __attribute__((ext_vector_type(8)));
typedef float  f32x4  __attribute__((ext_vector_type(4)));

// Round-to-nearest-even fp32 -> bf16 bits
__device__ __forceinline__ unsigned short f2bf(float x) {
    unsigned int u = __float_as_uint(x);
    return (unsigned short)((u + 0x7fffu + ((u >> 16) & 1u)) >> 16);
}
__device__ __forceinline__ ushort4 pack4v(f32x4 v) {
    return make_ushort4(f2bf(v[0]), f2bf(v[1]), f2bf(v[2]), f2bf(v[3]));
}
__device__ __forceinline__ f32x4 ntload4(const float* p) {
    return __builtin_nontemporal_load((const f32x4*)p);
}

// Load the wave's 16 B-fragments (32 W-cols, all 256 k) into registers.
// W: [256][128] fp32. 64 VGPRs; L2-hot after the first blocks touch it.
__device__ __forceinline__ void load_bfrags(const float* __restrict__ W,
                                            int c0, int q, int lo16, bf16x8* Bf)
{
    #pragma unroll
    for (int kt = 0; kt < 8; ++kt) {
        #pragma unroll
        for (int nt = 0; nt < 2; ++nt) {
            const float* p = W + (size_t)(kt * 32 + q * 8) * 128 + c0 + nt * 16 + lo16;
            union { unsigned short u[8]; bf16x8 v; } tmp;
            #pragma unroll
            for (int j = 0; j < 8; ++j) tmp.u[j] = f2bf(p[(size_t)j * 128]);
            Bf[kt * 2 + nt] = tmp.v;
        }
    }
}

// K1: layer3 (mean16(x3)|x2 @ W2, relu, mean16) FUSED with layer2
// ( [h2m|x1] @ W1, relu ). Each block owns 64 fused rows -> 4 h2m rows ->
// 4 h1 rows. h2m never leaves the block (LDS reuse); h1 [4096][128] fp32 out.
__global__ __launch_bounds__(NTHR, 4)
void k1_kernel(const float* __restrict__ x3,
               const float* __restrict__ x2,
               const float* __restrict__ x1,
               const float* __restrict__ W2,
               const float* __restrict__ b2,
               const float* __restrict__ W1,
               const float* __restrict__ b1,
               float* __restrict__ h1)     // [4096][128]
{
    __shared__ unsigned short A[64][264];  // bf16 bits; stride 264 -> <=2-way banks
    const int t  = threadIdx.x;
    const int m0 = blockIdx.x * 64;

    // ---- Phase 1: stream x3 (mean over 16) + x2 into bf16 A-tile ----
    {
        const int r8 = t >> 5;
        const int fo = (t & 31) * 4;
        for (int rr = r8; rr < 64; rr += 8) {
            const int m = m0 + rr;
            const float* dp = x3 + (size_t)m * 2048 + fo;
            f32x4 s = ntload4(dp);
            #pragma unroll
            for (int k = 1; k < 16; ++k) s += ntload4(dp + k * 128);
            s *= (1.0f / 16.0f);
            f32x4 sh = ntload4(x2 + (size_t)m * 128 + fo);
            *(ushort4*)&A[rr][fo]       = pack4v(s);
            *(ushort4*)&A[rr][128 + fo] = pack4v(sh);
        }
    }

    const int l    = t & 63;
    const int w    = t >> 6;
    const int lo16 = l & 15;
    const int q    = l >> 4;
    const int c0   = w * 32;

    bf16x8 Bf[16];
    load_bfrags(W2, c0, q, lo16, Bf);
    __syncthreads();

    // ---- Phase 2: layer-3 GEMM (LDS + matrix pipe only) ----
    f32x4 acc[4][2];
    #pragma unroll
    for (int mt = 0; mt < 4; ++mt) {
        acc[mt][0] = (f32x4){0.f, 0.f, 0.f, 0.f};
        acc[mt][1] = (f32x4){0.f, 0.f, 0.f, 0.f};
    }
    #pragma unroll
    for (int kt = 0; kt < 8; ++kt) {
        #pragma unroll
        for (int mt = 0; mt < 4; ++mt) {
            bf16x8 Af = *(const bf16x8*)&A[mt * 16 + lo16][kt * 32 + q * 8];
            acc[mt][0] = __builtin_amdgcn_mfma_f32_16x16x32_bf16(Af, Bf[kt * 2 + 0], acc[mt][0], 0, 0, 0);
            acc[mt][1] = __builtin_amdgcn_mfma_f32_16x16x32_bf16(Af, Bf[kt * 2 + 1], acc[mt][1], 0, 0, 0);
        }
    }

    // ---- Epilogue A: bias+relu, reduce-16 -> 4 h2m rows, packed into A rows 0..3.
    // A is dead after the sync; rows 4..15 keep stale-but-finite bf16 garbage.
    // Matmul rows are independent, so garbage rows only corrupt outputs we discard.
    const float bn0 = b2[c0 + lo16];
    const float bn1 = b2[c0 + 16 + lo16];
    __syncthreads();   // everyone done reading A
    #pragma unroll
    for (int mt = 0; mt < 4; ++mt) {
        float v0 = 0.f, v1 = 0.f;
        #pragma unroll
        for (int r = 0; r < 4; ++r) {
            v0 += fmaxf(acc[mt][0][r] + bn0, 0.0f);
            v1 += fmaxf(acc[mt][1][r] + bn1, 0.0f);
        }
        v0 += __shfl_xor(v0, 16, 64); v0 += __shfl_xor(v0, 32, 64);
        v1 += __shfl_xor(v1, 16, 64); v1 += __shfl_xor(v1, 32, 64);
        if (q == 0) *(unsigned short*)&A[mt][c0 + lo16]      = f2bf(v0 * 0.0625f);
        if (q == 1) *(unsigned short*)&A[mt][c0 + 16 + lo16] = f2bf(v1 * 0.0625f);
    }
    // x1 half of the 4 layer-2 A-rows: wave w loads row (b*4+w)
    if (l < 32) {
        f32x4 sh = ntload4(x1 + (size_t)(blockIdx.x * 4 + w) * 128 + l * 4);
        *(ushort4*)&A[w][128 + l * 4] = pack4v(sh);
    }
    load_bfrags(W1, c0, q, lo16, Bf);   // reuse the same 64 VGPRs
    __syncthreads();

    // ---- Phase 3: 4-row layer-2 GEMM; only MFMA rows 0..3 (q==0) are valid ----
    f32x4 a20 = (f32x4){0.f, 0.f, 0.f, 0.f};
    f32x4 a21 = (f32x4){0.f, 0.f, 0.f, 0.f};
    #pragma unroll
    for (int kt = 0; kt < 8; ++kt) {
        bf16x8 Af = *(const bf16x8*)&A[lo16][kt * 32 + q * 8];
        a20 = __builtin_amdgcn_mfma_f32_16x16x32_bf16(Af, Bf[kt * 2 + 0], a20, 0, 0, 0);
        a21 = __builtin_amdgcn_mfma_f32_16x16x32_bf16(Af, Bf[kt * 2 + 1], a21, 0, 0, 0);
    }
    if (q == 0) {
        const float c1a = b1[c0 + lo16];
        const float c1b = b1[c0 + 16 + lo16];
        float* hp = h1 + (size_t)(blockIdx.x * 4) * 128;
        #pragma unroll
        for (int r = 0; r < 4; ++r) {
            hp[r * 128 + c0 + lo16]      = fmaxf(a20[r] + c1a, 0.0f);
            hp[r * 128 + c0 + 16 + lo16] = fmaxf(a21[r] + c1b, 0.0f);
        }
    }
}

// K2: layer1 ( [mean16(h1)|x0] @ W0, relu ) fused with z = h0 @ lin1_W + b and
// per-block BatchNorm partial sums. 16 blocks x 16 rows. h0 never leaves LDS.
__global__ __launch_bounds__(NTHR)
void k2_kernel(const float* __restrict__ h1,    // [4096][128]
               const float* __restrict__ x0,    // [256][128]
               const float* __restrict__ W0,
               const float* __restrict__ b0,
               const float* __restrict__ l1W,   // [128][8]
               const float* __restrict__ l1b,   // [8]
               float* __restrict__ z_ws,        // [256][8]
               float* __restrict__ part)        // [2][16][8]: sums, sumsq
{
    __shared__ unsigned short A[16][264];
    __shared__ float zh[16][132];   // h0 tile fp32, padded
    __shared__ float w1s[128 * 8];
    __shared__ float zs[16][9];
    const int t  = threadIdx.x;
    const int m0 = blockIdx.x * 16;

    // Phase 1: A-tile = [mean16(h1 group m) | x0 row m], bf16
    {
        const int r8 = t >> 5;
        const int fo = (t & 31) * 4;
        #pragma unroll
        for (int rr = r8; rr < 16; rr += 8) {
            const int m = m0 + rr;
            const float* dp = h1 + (size_t)m * 2048 + fo;
            f32x4 s = *(const f32x4*)dp;
            #pragma unroll
            for (int k = 1; k < 16; ++k) s += *(const f32x4*)(dp + k * 128);
            s *= (1.0f / 16.0f);
            f32x4 sh = *(const f32x4*)(x0 + (size_t)m * 128 + fo);
            *(ushort4*)&A[rr][fo]       = pack4v(s);
            *(ushort4*)&A[rr][128 + fo] = pack4v(sh);
        }
    }
    *(f32x4*)&w1s[t * 4] = *(const f32x4*)&l1W[t * 4];

    const int l    = t & 63;
    const int w    = t >> 6;
    const int lo16 = l & 15;
    const int q    = l >> 4;
    const int c0   = w * 32;

    bf16x8 Bf[16];
    load_bfrags(W0, c0, q, lo16, Bf);
    __syncthreads();

    f32x4 a0 = (f32x4){0.f, 0.f, 0.f, 0.f};
    f32x4 a1 = (f32x4){0.f, 0.f, 0.f, 0.f};
    #pragma unroll
    for (int kt = 0; kt < 8; ++kt) {
        bf16x8 Af = *(const bf16x8*)&A[lo16][kt * 32 + q * 8];
        a0 = __builtin_amdgcn_mfma_f32_16x16x32_bf16(Af, Bf[kt * 2 + 0], a0, 0, 0, 0);
        a1 = __builtin_amdgcn_mfma_f32_16x16x32_bf16(Af, Bf[kt * 2 + 1], a1, 0, 0, 0);
    }
    const float bb0 = b0[c0 + lo16];
    const float bb1 = b0[c0 + 16 + lo16];
    #pragma unroll
    for (int r = 0; r < 4; ++r) {
        zh[q * 4 + r][c0 + lo16]      = fmaxf(a0[r] + bb0, 0.0f);
        zh[q * 4 + r][c0 + 16 + lo16] = fmaxf(a1[r] + bb1, 0.0f);
    }
    __syncthreads();

    if (t < 128) {   // z[m][j] = h0[m] . l1W[:,j] + b
        const int m = t >> 3, j = t & 7;
        float s = l1b[j];
        #pragma unroll
        for (int c = 0; c < 128; ++c) s += zh[m][c] * w1s[c * 8 + j];
        z_ws[(size_t)(m0 + m) * 8 + j] = s;
        zs[m][j] = s;
    }
    __syncthreads();
    if (t < 8) {     // per-block BN partials (plain stores; no zero-init needed)
        float s = 0.f, qq = 0.f;
        #pragma unroll
        for (int m = 0; m < 16; ++m) { const float v = zs[m][t]; s += v; qq += v * v; }
        part[blockIdx.x * 8 + t]       = s;
        part[128 + blockIdx.x * 8 + t] = qq;
    }
}

// K3: reduce BN partials, normalize, lin2 + sigmoid. Trivial.
__global__ __launch_bounds__(NTHR)
void k3_kernel(const float* __restrict__ part,   // [2][16][8]
               const float* __restrict__ z_ws,   // [256][8]
               const float* __restrict__ gamma,
               const float* __restrict__ beta,
               const float* __restrict__ l2W,    // [8][2]
               const float* __restrict__ l2b,    // [2]
               float* __restrict__ out)          // [256][2]
{
    __shared__ float scale_s[8], shift_s[8];
    __shared__ float w2s[16], b2s[2];
    const int t = threadIdx.x;
    if (t < 16) w2s[t] = l2W[t];
    if (t < 2)  b2s[t] = l2b[t];
    if (t < 8) {
        float s = 0.f, qq = 0.f;
        #pragma unroll
        for (int p = 0; p < 16; ++p) {
            s  += part[p * 8 + t];
            qq += part[128 + p * 8 + t];
        }
        const float mu  = s * (1.0f / 256.0f);
        const float var = qq * (1.0f / 256.0f) - mu * mu;
        const float sc  = gamma[t] * rsqrtf(var + 1e-5f);
        scale_s[t] = sc;
        shift_s[t] = beta[t] - mu * sc;
    }
    __syncthreads();
    float o0 = b2s[0], o1 = b2s[1];
    const float* zr = z_ws + (size_t)t * 8;
    #pragma unroll
    for (int j = 0; j < 8; ++j) {
        const float zn = zr[j] * scale_s[j] + shift_s[j];
        o0 += zn * w2s[j * 2 + 0];
        o1 += zn * w2s[j * 2 + 1];
    }
    out[t * 2 + 0] = 1.0f / (1.0f + expf(-o0));
    out[t * 2 + 1] = 1.0f / (1.0f + expf(-o1));
}

extern "C" void kernel_launch(void* const* d_in, const int* in_sizes, int n_in,
                              void* d_out, int out_size, void* d_ws, size_t ws_size,
                              hipStream_t stream)
{
    const float* x0    = (const float*)d_in[0];
    const float* x1    = (const float*)d_in[1];
    const float* x2    = (const float*)d_in[2];
    const float* x3    = (const float*)d_in[3];
    const float* W0    = (const float*)d_in[4];
    const float* b0    = (const float*)d_in[5];
    const float* W1    = (const float*)d_in[6];
    const float* b1    = (const float*)d_in[7];
    const float* W2    = (const float*)d_in[8];
    const float* b2    = (const float*)d_in[9];
    const float* l1W   = (const float*)d_in[10];
    const float* l1b   = (const float*)d_in[11];
    const float* gamma = (const float*)d_in[12];
    const float* beta  = (const float*)d_in[13];
    const float* l2W   = (const float*)d_in[14];
    const float* l2b   = (const float*)d_in[15];
    float* out = (float*)d_out;

    float* h1   = (float*)d_ws;                  // [4096][128] fp32 = 2 MB
    float* z_ws = h1 + (size_t)4096 * 128;       // [256][8]
    float* part = z_ws + (size_t)256 * 8;        // [2][16][8]

    // K1: layers 3+2 fused; h2m never hits HBM.
    hipLaunchKernelGGL(k1_kernel, dim3(65536 / 64), dim3(NTHR), 0, stream,
                       x3, x2, x1, W2, b2, W1, b1, h1);
    // K2: layer 1 + classifier z + BN partials; h0 never hits HBM.
    hipLaunchKernelGGL(k2_kernel, dim3(16), dim3(NTHR), 0, stream,
                       h1, x0, W0, b0, l1W, l1b, z_ws, part);
    // K3: BN finalize + lin2 + sigmoid.
    hipLaunchKernelGGL(k3_kernel, dim3(1), dim3(NTHR), 0, stream,
                       part, z_ws, gamma, beta, l2W, l2b, out);
}